// Round 7
// baseline (1211.013 us; speedup 1.0000x reference)
//
#include <hip/hip_runtime.h>
#include <math.h>

// NaryTreeLSTM on MI355X — round 7: two-stage per level.
// Stage 1 (gate_gemm): m97-style 128x128 MFMA GEMM, BK=64, single-buffered
//   32KB LDS via global_load_lds(16B). Epilogue: i,o=sig->fp16; u=tanh->fp16;
//   f0,f1 = sig * child_c -> fp32 (folds the scattered child-c read in).
// Stage 2 (combine): c = i*u + fc0 + fc1; h = o*tanh(c); writes c fp32 and
//   Hs=h0+h1 bf16 into the parent's frag-major Z.
// Round-6 failure mode fixed: streamed operands live in LDS, not VGPRs
// (round 6 needed 96 VGPRs of load buffers; compiler gave 84 total ->
// pipeline collapsed to serialized loads, MfmaUtil 8.6%).

#define LEAF_N 65536

typedef __attribute__((ext_vector_type(8))) short bf16x8;
typedef __attribute__((ext_vector_type(4))) float f32x4;
typedef unsigned short u16;

__device__ __forceinline__ float sigf(float x) { return 1.0f / (1.0f + expf(-x)); }

__device__ __forceinline__ u16 f2bf(float f) {
    union { float f; unsigned u; } v; v.f = f;
    unsigned r = v.u + 0x7fffu + ((v.u >> 16) & 1u);   // RNE
    return (u16)(r >> 16);
}

// Z region offset (elems). d>=4: packed back-to-back (tile-aligned).
// d<=3: dedicated full 16-row tiles after the main area (8192 elems each).
// NOTE: gate_gemm reads up to 128 rows per tile; worst case (d=5) reads
// exactly to the end of the +32768-elem pad. Do not shrink the pad.
__host__ __device__ __forceinline__ size_t zoffD(int d) {
    return (d >= 4) ? (size_t)(65536 - (2 << d)) * 512
                    : (size_t)65536 * 512 + (size_t)(3 - d) * 8192;
}

__device__ __forceinline__ void gld_lds16(const u16* g, u16* s) {
    __builtin_amdgcn_global_load_lds(
        (const __attribute__((address_space(1))) void*)g,
        (__attribute__((address_space(3))) void*)s, 16, 0, 0);
}

// ---------------- weight packing: fp32 -> bf16, fragment-major ----------------
// frag(tile,kc) lane l elem j <-> Mat[tile*16+(l&15)][kc*32+(l>>4)*8+j]
// Wbig rows: [0:256)=[Wi|Ui],[256:512)=[Wo|Uo],[512:768)=[Wu|Uu],
//   [768:1024)=[Wf|Wfk0],[1024:1280)=[Wf|Wfk1]  (K=512, KCN=16)
// Wleaf rows: [Wi;Wo;Wu] (K=256, KCN=8)
__global__ __launch_bounds__(256) void pack_weights(
    const float* __restrict__ Wi, const float* __restrict__ bi,
    const float* __restrict__ Wf, const float* __restrict__ bf,
    const float* __restrict__ Wo, const float* __restrict__ bo,
    const float* __restrict__ Wu, const float* __restrict__ bu,
    const float* __restrict__ Ui, const float* __restrict__ Uo,
    const float* __restrict__ Uu, const float* __restrict__ Wfk,
    u16* __restrict__ Wpk, u16* __restrict__ WpkL,
    float* __restrict__ bbig, float* __restrict__ bleaf)
{
    int idx = blockIdx.x * 256 + threadIdx.x;
    const int NWB = 1280 * 512;
    const int NWL = 768 * 256;
    if (idx < NWB) {
        int j = idx & 7, l = (idx >> 3) & 63, kc = (idx >> 9) & 15, nt = idx >> 13;
        int row = nt * 16 + (l & 15);
        int k = kc * 32 + ((l >> 4) << 3) + j;
        int g = row >> 8, rr = row & 255;
        float v;
        if (k < 256) {
            const float* W = (g == 0) ? Wi : (g == 1) ? Wo : (g == 2) ? Wu : Wf;
            v = W[rr * 256 + k];
        } else {
            int kk = k - 256;
            v = (g == 0) ? Ui[rr * 256 + kk]
              : (g == 1) ? Uo[rr * 256 + kk]
              : (g == 2) ? Uu[rr * 256 + kk]
              : (g == 3) ? Wfk[rr * 256 + kk]
                         : Wfk[65536 + rr * 256 + kk];
        }
        Wpk[idx] = f2bf(v);
    } else if (idx < NWB + NWL) {
        int q = idx - NWB;
        int j = q & 7, l = (q >> 3) & 63, kc = (q >> 9) & 7, nt = q >> 12;
        int row = nt * 16 + (l & 15);
        int k = kc * 32 + ((l >> 4) << 3) + j;
        int g = row >> 8, rr = row & 255;
        const float* W = (g == 0) ? Wi : (g == 1) ? Wo : Wu;
        WpkL[q] = f2bf(W[rr * 256 + k]);
    } else if (idx < NWB + NWL + 1280) {
        int r = idx - NWB - NWL;
        int g = r >> 8, rr = r & 255;
        bbig[r] = (g == 0) ? bi[rr] : (g == 1) ? bo[rr] : (g == 2) ? bu[rr] : bf[rr];
    } else if (idx < NWB + NWL + 1280 + 768) {
        int r = idx - NWB - NWL - 1280;
        int g = r >> 8, rr = r & 255;
        bleaf[r] = (g == 0) ? bi[rr] : (g == 1) ? bo[rr] : bu[rr];
    }
}

// ---------------- x -> bf16, scattered into fragment-major Z / Xpk ----------
__global__ __launch_bounds__(256) void cvt_all(
    const float* __restrict__ x, u16* __restrict__ Zbuf, u16* __restrict__ Xpk)
{
    int idx = blockIdx.x * 256 + threadIdx.x;
    if (idx >= 131071 * 32) return;
    int row = idx >> 5, k8 = idx & 31;
    const float* s = x + (size_t)row * 256 + k8 * 8;
    u16 r[8];
#pragma unroll
    for (int i = 0; i < 8; i++) r[i] = f2bf(s[i]);
    int kc = k8 >> 2;
    if (row < 65535) {
        int d = 31 - __clz(row + 1);
        int jn = row - ((1 << d) - 1);
        int l = (jn & 15) + ((k8 & 3) << 4);
        size_t dst = zoffD(d) + ((size_t)((jn >> 4) * 16 + kc) * 64 + l) * 8;
        *(uint4*)(Zbuf + dst) = *(uint4*)r;
    } else {
        int jn = row - 65535;
        int l = (jn & 15) + ((k8 & 3) << 4);
        size_t dst = ((size_t)((jn >> 4) * 8 + kc) * 64 + l) * 8;
        *(uint4*)(Xpk + dst) = *(uint4*)r;
    }
}

// ---------------- stage 1: gate GEMM + activation epilogue ----------------
// 256 thr = 4 waves (2m x 2n), tile 128 rows x 128 cols, BK=64.
// blockIdx.y = col-tile (gate g = bn>>1 uniform per block).
template<int KCN>
__global__ __launch_bounds__(256) void gate_gemm(
    const u16* __restrict__ Zpk, const u16* __restrict__ Wpk,
    const float* __restrict__ bias, const float* __restrict__ csrc,
    _Float16* __restrict__ Ghalf, float* __restrict__ Gfc, int n)
{
    __shared__ u16 As[16 * 512];
    __shared__ u16 Bs[16 * 512];
    const int tid = threadIdx.x, wave = tid >> 6, lane = tid & 63;
    const int bm = blockIdx.x * 128, bn = blockIdx.y;
    const int wm = wave >> 1, wn = wave & 1;
    const int cc = lane & 15, rq = (lane >> 4) * 4;

    f32x4 acc[4][4] = {};
    const u16* Ag = Zpk + (size_t)(bm >> 4) * KCN * 512;
    const u16* Bg = Wpk + (size_t)(bn * 8) * KCN * 512;

    for (int ch = 0; ch < KCN / 2; ++ch) {
        const int kc0 = ch * 2;
#pragma unroll
        for (int q = 0; q < 8; ++q) {
            int fid = wave * 8 + q;                   // wave-uniform
            if (fid < 16) {
                int rt = fid >> 1, kc = fid & 1;
                gld_lds16(Ag + ((size_t)rt * KCN + kc0 + kc) * 512 + lane * 8,
                          As + fid * 512);
            } else {
                int f2 = fid - 16, nt = f2 >> 1, kc = f2 & 1;
                gld_lds16(Bg + ((size_t)nt * KCN + kc0 + kc) * 512 + lane * 8,
                          Bs + f2 * 512);
            }
        }
        __syncthreads();
#pragma unroll
        for (int kc = 0; kc < 2; ++kc) {
            bf16x8 af[4], bfr[4];
#pragma unroll
            for (int i = 0; i < 4; ++i)
                af[i] = *(const bf16x8*)(As + ((wm * 4 + i) * 2 + kc) * 512 + lane * 8);
#pragma unroll
            for (int j = 0; j < 4; ++j)
                bfr[j] = *(const bf16x8*)(Bs + ((wn * 4 + j) * 2 + kc) * 512 + lane * 8);
#pragma unroll
            for (int i = 0; i < 4; ++i)
#pragma unroll
                for (int j = 0; j < 4; ++j)
                    acc[i][j] = __builtin_amdgcn_mfma_f32_16x16x32_bf16(
                        af[i], bfr[j], acc[i][j], 0, 0, 0);
        }
        __syncthreads();
    }

    const int g = bn >> 1;   // gate: 0=i 1=o 2=u 3=f0 4=f1 (leaf: 0=i 1=o 2=u)
#pragma unroll
    for (int j = 0; j < 4; ++j) {
        const int col = bn * 128 + (wn * 4 + j) * 16 + cc;
        const float bb = bias[col];
#pragma unroll
        for (int i = 0; i < 4; ++i) {
            const int row0 = bm + (wm * 4 + i) * 16 + rq;
#pragma unroll
            for (int r = 0; r < 4; ++r) {
                const int row = row0 + r;
                if (row >= n) continue;
                const float v = acc[i][j][r] + bb;
                if (g == 2) {
                    Ghalf[(size_t)row * 768 + col] = (_Float16)tanhf(v);
                } else if (g < 2) {
                    Ghalf[(size_t)row * 768 + col] = (_Float16)sigf(v);
                } else {
                    const float cch = csrc[(size_t)(2 * row + (g - 3)) * 256
                                           + (col - g * 256)];
                    Gfc[(size_t)row * 512 + (col - 768)] = sigf(v) * cch;
                }
            }
        }
    }
}

// ---------------- stage 2: combine ----------------
// grid = npairs blocks x 256 thr; block p handles nodes 2p, 2p+1, thread h.
template<bool LEAF>
__global__ __launch_bounds__(256) void combine(
    const _Float16* __restrict__ Ghalf, const float* __restrict__ Gfc,
    float* __restrict__ cdst, u16* __restrict__ zparent)
{
    const int p = blockIdx.x, h = threadIdx.x;
    const size_t n0 = (size_t)2 * p;
    const _Float16* G0 = Ghalf + n0 * 768;
    const _Float16* G1 = G0 + 768;
    float i0 = (float)G0[h], o0 = (float)G0[256 + h], u0 = (float)G0[512 + h];
    float i1 = (float)G1[h], o1 = (float)G1[256 + h], u1 = (float)G1[512 + h];
    float c0 = i0 * u0, c1 = i1 * u1;
    if (!LEAF) {
        const float* F = Gfc + n0 * 512;
        c0 += F[h] + F[256 + h];
        c1 += F[512 + h] + F[768 + h];
    }
    float h0 = o0 * tanhf(c0), h1 = o1 * tanhf(c1);
    cdst[n0 * 256 + h] = c0;
    cdst[n0 * 256 + 256 + h] = c1;
    size_t a = (((size_t)(p >> 4) * 16 + 8 + (h >> 5)) * 64
                + (p & 15) + (((h >> 3) & 3) << 4)) * 8 + (h & 7);
    zparent[a] = f2bf(h0 + h1);
}

// ---------------- small levels (n<=16): gate-parallel GEMM -> pre ----------
__global__ __launch_bounds__(64) void small_gemm(
    const u16* __restrict__ Zpk, const u16* __restrict__ Wpk,
    const float* __restrict__ bias, float* __restrict__ pre, int n)
{
    const int lane = threadIdx.x;
    const int q = blockIdx.x;
    const int nt0 = (q >> 2) * 16 + (q & 3) * 4;
    const int cc = lane & 15, rq = (lane >> 4) * 4;

    f32x4 acc[4] = {};
    const u16* aB = Zpk + (size_t)lane * 8;
    const u16* bB = Wpk + ((size_t)nt0 * 16 * 64 + lane) * 8;

    bf16x8 aX, bX[4], aY, bY[4];
    aX = *(const bf16x8*)(aB);
#pragma unroll
    for (int j = 0; j < 4; ++j)
        bX[j] = *(const bf16x8*)(bB + (size_t)(j * 16) * 512);

#pragma unroll
    for (int kc = 0; kc < 16; kc += 2) {
        aY = *(const bf16x8*)(aB + (size_t)(kc + 1) * 512);
#pragma unroll
        for (int j = 0; j < 4; ++j)
            bY[j] = *(const bf16x8*)(bB + (size_t)(j * 16 + kc + 1) * 512);
#pragma unroll
        for (int j = 0; j < 4; ++j)
            acc[j] = __builtin_amdgcn_mfma_f32_16x16x32_bf16(aX, bX[j], acc[j], 0, 0, 0);
        if (kc + 2 < 16) {
            aX = *(const bf16x8*)(aB + (size_t)(kc + 2) * 512);
#pragma unroll
            for (int j = 0; j < 4; ++j)
                bX[j] = *(const bf16x8*)(bB + (size_t)(j * 16 + kc + 2) * 512);
        }
#pragma unroll
        for (int j = 0; j < 4; ++j)
            acc[j] = __builtin_amdgcn_mfma_f32_16x16x32_bf16(aY, bY[j], acc[j], 0, 0, 0);
    }

#pragma unroll
    for (int j = 0; j < 4; ++j) {
        int coln = (nt0 + j) * 16 + cc;
        float bb = bias[coln];
#pragma unroll
        for (int r = 0; r < 4; ++r) {
            int row = rq + r;
            if (row < n) pre[(size_t)row * 1280 + coln] = acc[j][r] + bb;
        }
    }
}

// ---------------- small-level epilogue (pre -> c, Hs; root -> out) ----------
__global__ __launch_bounds__(256) void epi_small(
    const float* __restrict__ pre, const float* __restrict__ csrc,
    float* __restrict__ c_out, u16* __restrict__ zparent,
    float* __restrict__ root_out, int npairs)
{
    int idx = blockIdx.x * 256 + threadIdx.x;
    if (root_out) {
        int h = idx;  // 256 threads
        const float* p = pre;
        float c = sigf(p[h]) * tanhf(p[512 + h])
                + sigf(p[768 + h]) * csrc[h]
                + sigf(p[1024 + h]) * csrc[256 + h];
        root_out[h] = sigf(p[256 + h]) * tanhf(c);
        root_out[256 + h] = c;
        return;
    }
    if (idx >= npairs * 256) return;
    int pI = idx >> 8, h = idx & 255;
    int n0 = 2 * pI;
    const float* p0 = pre + (size_t)n0 * 1280;
    const float* p1 = p0 + 1280;
    float c0 = sigf(p0[h]) * tanhf(p0[512 + h])
             + sigf(p0[768 + h]) * csrc[(size_t)(2 * n0) * 256 + h]
             + sigf(p0[1024 + h]) * csrc[(size_t)(2 * n0 + 1) * 256 + h];
    float c1 = sigf(p1[h]) * tanhf(p1[512 + h])
             + sigf(p1[768 + h]) * csrc[(size_t)(2 * n0 + 2) * 256 + h]
             + sigf(p1[1024 + h]) * csrc[(size_t)(2 * n0 + 3) * 256 + h];
    float h0 = sigf(p0[256 + h]) * tanhf(c0);
    float h1 = sigf(p1[256 + h]) * tanhf(c1);
    c_out[(size_t)n0 * 256 + h] = c0;
    c_out[(size_t)(n0 + 1) * 256 + h] = c1;
    size_t a = ((size_t)((pI >> 4) * 16 + 8 + (h >> 5)) * 64
                + (pI & 15) + (((h >> 3) & 3) << 4)) * 8 + (h & 7);
    zparent[a] = f2bf(h0 + h1);
}

// ---------------- launch ----------------
extern "C" void kernel_launch(void* const* d_in, const int* in_sizes, int n_in,
                              void* d_out, int out_size, void* d_ws, size_t ws_size,
                              hipStream_t stream)
{
    const float* x   = (const float*)d_in[0];
    const float* Wi  = (const float*)d_in[1];
    const float* bi  = (const float*)d_in[2];
    const float* Wf  = (const float*)d_in[3];
    const float* bf  = (const float*)d_in[4];
    const float* Wo  = (const float*)d_in[5];
    const float* bo  = (const float*)d_in[6];
    const float* Wu  = (const float*)d_in[7];
    const float* bu  = (const float*)d_in[8];
    const float* Ui  = (const float*)d_in[9];
    const float* Uo  = (const float*)d_in[10];
    const float* Uu  = (const float*)d_in[11];
    const float* Wfk = (const float*)d_in[12];
    float* out = (float*)d_out;
    char* ws   = (char*)d_ws;
    (void)ws_size; (void)in_sizes; (void)n_in; (void)out_size;

    size_t off = 0;
    u16* Wpk  = (u16*)(ws + off); off += (size_t)1280 * 512 * 2;
    u16* WpkL = (u16*)(ws + off); off += (size_t)768 * 256 * 2;
    float* bbig  = (float*)(ws + off); off += 1280 * 4;
    float* bleaf = (float*)(ws + off); off += 768 * 4 + 192;                  // 256B align
    u16* Xpk  = (u16*)(ws + off); off += (size_t)65536 * 256 * 2;             // 32 MB
    u16* Zbuf = (u16*)(ws + off); off += ((size_t)65536 * 512 + 32768) * 2;   // 64 MB + pad
    float* cA = (float*)(ws + off); off += (size_t)65536 * 256 * 4;           // 64 MB
    float* cB = (float*)(ws + off); off += (size_t)32768 * 256 * 4;           // 32 MB
    float* pre_small = (float*)(ws + off); off += (size_t)16 * 1280 * 4;
    _Float16* Ghalf = (_Float16*)(ws + off); off += (size_t)65536 * 768 * 2;  // 100 MB
    float* Gfc = (float*)(ws + off); off += (size_t)32768 * 512 * 4;          // 67 MB

    // 1) pack weights + scatter x -> frag-major bf16
    pack_weights<<<3336, 256, 0, stream>>>(Wi, bi, Wf, bf, Wo, bo, Wu, bu,
                                           Ui, Uo, Uu, Wfk, Wpk, WpkL, bbig, bleaf);
    cvt_all<<<16385, 256, 0, stream>>>(x, Zbuf, Xpk);

    // 2) leaf: gate GEMM (i,o,u) + combine -> cA, Hs into Z_15
    gate_gemm<8><<<dim3(LEAF_N / 128, 6), 256, 0, stream>>>(
        Xpk, WpkL, bleaf, nullptr, Ghalf, nullptr, LEAF_N);
    combine<true><<<LEAF_N / 2, 256, 0, stream>>>(
        Ghalf, nullptr, cA, Zbuf + zoffD(15));

    // 3) internal levels d=15..5: gate GEMM (5 gates, f*c fused) + combine
    for (int d = 15; d >= 5; d--) {
        int n = 1 << d;
        float* csrc = (d & 1) ? cA : cB;
        float* cdst = (d & 1) ? cB : cA;
        gate_gemm<16><<<dim3((n + 127) / 128, 10), 256, 0, stream>>>(
            Zbuf + zoffD(d), Wpk, bbig, csrc, Ghalf, Gfc, n);
        combine<false><<<n / 2, 256, 0, stream>>>(
            Ghalf, Gfc, cdst, Zbuf + zoffD(d - 1));
    }

    // 4) small levels d=4..1: gate-parallel gemm (pre in L2) + epilogue
    for (int d = 4; d >= 1; d--) {
        int n = 1 << d;
        float* csrc = (d & 1) ? cA : cB;
        float* cdst = (d & 1) ? cB : cA;
        small_gemm<<<20, 64, 0, stream>>>(Zbuf + zoffD(d), Wpk, bbig, pre_small, n);
        epi_small<<<n / 2, 256, 0, stream>>>(pre_small, csrc, cdst,
                                             Zbuf + zoffD(d - 1), nullptr, n / 2);
    }

    // 5) root: gemm + epilogue straight to out = [h(256)|c(256)]
    small_gemm<<<20, 64, 0, stream>>>(Zbuf + zoffD(0), Wpk, bbig, pre_small, 1);
    epi_small<<<1, 256, 0, stream>>>(pre_small, cB, nullptr, nullptr, out, 0);
}

// Round 8
// 992.517 us; speedup vs baseline: 1.2201x; 1.2201x over previous
//
#include <hip/hip_runtime.h>
#include <math.h>

// NaryTreeLSTM on MI355X — round 8: R2's proven 128x128 LDS gemm + activated
// fp16 gate output (halves stage-1 write traffic, no csrc in the GEMM), lean
// combine (gates+csrc -> c fp32 + Hs bf16 into parent Z), R6's small-level
// path for d<=4. R7 post-mortem: csrc gather in the GEMM epilogue + Gfc fp32
// round-trip made the "fused" gemm slower than R2's plain one.

#define LEAF_N 65536

typedef __attribute__((ext_vector_type(8))) short bf16x8;
typedef __attribute__((ext_vector_type(4))) float f32x4;
typedef unsigned short u16;

__device__ __forceinline__ float sigf(float x) { return 1.0f / (1.0f + expf(-x)); }

__device__ __forceinline__ u16 f2bf(float f) {
    union { float f; unsigned u; } v; v.f = f;
    unsigned r = v.u + 0x7fffu + ((v.u >> 16) & 1u);   // RNE
    return (u16)(r >> 16);
}

// row-major Z offset (elems) for levels d in [5,15]
__host__ __device__ __forceinline__ size_t zrowOff(int d) {
    return (size_t)(65536 - (2 << d)) * 512;
}

// ---------------- weight packing ----------------
// Wrow: row-major 1280x512 ([i|Ui],[o|Uo],[u|Uu],[f|Wfk0],[f|Wfk1])
// Wfrag: frag-major same matrix (for small_gemm):
//   addr = ((nt*16+kc)*64 + l)*8 + j ; row=nt*16+(l&15), k=kc*32+(l>>4)*8+j
// WleafRow: row-major 768x256 ([i;o;u])
__global__ __launch_bounds__(256) void pack_weights(
    const float* __restrict__ Wi, const float* __restrict__ bi,
    const float* __restrict__ Wf, const float* __restrict__ bf,
    const float* __restrict__ Wo, const float* __restrict__ bo,
    const float* __restrict__ Wu, const float* __restrict__ bu,
    const float* __restrict__ Ui, const float* __restrict__ Uo,
    const float* __restrict__ Uu, const float* __restrict__ Wfk,
    u16* __restrict__ Wrow, u16* __restrict__ Wfrag, u16* __restrict__ WleafRow,
    float* __restrict__ bbig, float* __restrict__ bleaf)
{
    int idx = blockIdx.x * 256 + threadIdx.x;
    const int NWB = 1280 * 512;   // 655360
    const int NWL = 768 * 256;    // 196608

    auto bigval = [&](int row, int k) -> float {
        int g = row >> 8, rr = row & 255;
        if (k < 256) {
            const float* W = (g == 0) ? Wi : (g == 1) ? Wo : (g == 2) ? Wu : Wf;
            return W[rr * 256 + k];
        }
        int kk = k - 256;
        return (g == 0) ? Ui[rr * 256 + kk]
             : (g == 1) ? Uo[rr * 256 + kk]
             : (g == 2) ? Uu[rr * 256 + kk]
             : (g == 3) ? Wfk[rr * 256 + kk]
                        : Wfk[65536 + rr * 256 + kk];
    };

    if (idx < NWB) {                                   // row-major big
        Wrow[idx] = f2bf(bigval(idx >> 9, idx & 511));
    } else if (idx < 2 * NWB) {                        // frag-major big
        int q = idx - NWB;
        int j = q & 7, l = (q >> 3) & 63, kc = (q >> 9) & 15, nt = q >> 13;
        int row = nt * 16 + (l & 15);
        int k = kc * 32 + ((l >> 4) << 3) + j;
        Wfrag[q] = f2bf(bigval(row, k));
    } else if (idx < 2 * NWB + NWL) {                  // row-major leaf
        int q = idx - 2 * NWB;
        int r = q >> 8, k = q & 255;
        int g = r >> 8, rr = r & 255;
        const float* W = (g == 0) ? Wi : (g == 1) ? Wo : Wu;
        WleafRow[q] = f2bf(W[rr * 256 + k]);
    } else if (idx < 2 * NWB + NWL + 1280) {
        int r = idx - 2 * NWB - NWL;
        int g = r >> 8, rr = r & 255;
        bbig[r] = (g == 0) ? bi[rr] : (g == 1) ? bo[rr] : (g == 2) ? bu[rr] : bf[rr];
    } else if (idx < 2 * NWB + NWL + 1280 + 768) {
        int r = idx - 2 * NWB - NWL - 1280;
        int g = r >> 8, rr = r & 255;
        bleaf[r] = (g == 0) ? bi[rr] : (g == 1) ? bo[rr] : bu[rr];
    }
}

// ---------------- x -> bf16 conversion ----------------
// d>=5: row-major Zrow (rows n x 512, x in cols 0..255)
// d<=4: frag-major 16-row tile at Ztiles + (4-d)*8192, x in kc 0..7
// leaf: row-major Xbf (65536 x 256)
__global__ __launch_bounds__(256) void cvt_all(
    const float* __restrict__ x, u16* __restrict__ Zrow,
    u16* __restrict__ Ztiles, u16* __restrict__ Xbf)
{
    int idx = blockIdx.x * 256 + threadIdx.x;
    if (idx >= 131071 * 32) return;
    int row = idx >> 5, k8 = idx & 31;           // k = k8*8..+7
    const float* s = x + (size_t)row * 256 + k8 * 8;
    u16 r[8];
#pragma unroll
    for (int i = 0; i < 8; i++) r[i] = f2bf(s[i]);
    if (row < 65535) {
        int d = 31 - __clz(row + 1);
        int jn = row - ((1 << d) - 1);
        if (d >= 5) {
            *(uint4*)(Zrow + zrowOff(d) + (size_t)jn * 512 + k8 * 8) = *(uint4*)r;
        } else {
            int kc = k8 >> 2;                      // 0..7
            int l = (jn & 15) + ((k8 & 3) << 4);
            size_t dst = (size_t)(4 - d) * 8192 + ((size_t)kc * 64 + l) * 8;
            *(uint4*)(Ztiles + dst) = *(uint4*)r;
        }
    } else {
        int jn = row - 65535;
        *(uint4*)(Xbf + (size_t)jn * 256 + k8 * 8) = *(uint4*)r;
    }
}

// ---------------- stage 1: gate GEMM (R2 body) + activation epilogue -------
// C = act(A @ B^T + bias) -> fp16. act: tanh for cols [512,768), sigmoid else.
__global__ __launch_bounds__(256) void gate_gemm(
    const u16* __restrict__ A, int lda, int M,
    const u16* __restrict__ B, int ldb, int Kdim,
    const float* __restrict__ bias, _Float16* __restrict__ G, int NC)
{
    constexpr int LP = 72;
    __shared__ u16 As[128 * LP];
    __shared__ u16 Bs[128 * LP];

    const int tid  = threadIdx.x;
    const int wave = tid >> 6;
    const int lane = tid & 63;
    const int bm = blockIdx.x * 128;
    const int bn = blockIdx.y * 128;

    const int srow = tid >> 3;
    const int scol = (tid & 7) * 8;
    const int wm = (wave >> 1) * 64;
    const int wn = (wave & 1) * 64;
    const int lm = lane & 15;
    const int kq = (lane >> 4) * 8;

    f32x4 acc[4][4] = {};

    for (int k0 = 0; k0 < Kdim; k0 += 64) {
#pragma unroll
        for (int p = 0; p < 4; p++) {
            int r = srow + p * 32;
            int gr = bm + r;
            uint4 av = make_uint4(0u, 0u, 0u, 0u);
            if (gr < M) av = *(const uint4*)(A + (size_t)gr * lda + k0 + scol);
            *(uint4*)(As + r * LP + scol) = av;
            uint4 bv = *(const uint4*)(B + (size_t)(bn + r) * ldb + k0 + scol);
            *(uint4*)(Bs + r * LP + scol) = bv;
        }
        __syncthreads();

#pragma unroll
        for (int kk = 0; kk < 64; kk += 32) {
            bf16x8 af[4], bfr[4];
#pragma unroll
            for (int i = 0; i < 4; i++)
                af[i] = *(const bf16x8*)(As + (wm + i * 16 + lm) * LP + kk + kq);
#pragma unroll
            for (int j = 0; j < 4; j++)
                bfr[j] = *(const bf16x8*)(Bs + (wn + j * 16 + lm) * LP + kk + kq);
#pragma unroll
            for (int i = 0; i < 4; i++)
#pragma unroll
                for (int j = 0; j < 4; j++)
                    acc[i][j] = __builtin_amdgcn_mfma_f32_16x16x32_bf16(
                        af[i], bfr[j], acc[i][j], 0, 0, 0);
        }
        __syncthreads();
    }

    const int cr0 = (lane >> 4) * 4;
    const int ccc = lane & 15;
#pragma unroll
    for (int i = 0; i < 4; i++) {
#pragma unroll
        for (int reg = 0; reg < 4; reg++) {
            int r = bm + wm + i * 16 + cr0 + reg;
            if (r >= M) continue;
#pragma unroll
            for (int j = 0; j < 4; j++) {
                int cn = bn + wn + j * 16 + ccc;
                float v = acc[i][j][reg] + bias[cn];
                float a = ((cn >> 8) == 2) ? tanhf(v) : sigf(v);
                G[(size_t)r * NC + cn] = (_Float16)a;
            }
        }
    }
}

// ---------------- stage 2: combine ----------------
// block p handles nodes 2p,2p+1; thread = h. G holds activated gates.
// zrow_parent != null: parent is row-major level (store at p*512+256+h).
// else zfrag_parent: frag-major 16-row tile (d=5 -> d=4 handoff).
template<bool LEAF>
__global__ __launch_bounds__(256) void combine(
    const _Float16* __restrict__ G, const float* __restrict__ csrc,
    float* __restrict__ cdst, u16* __restrict__ zrow_parent,
    u16* __restrict__ zfrag_parent)
{
    constexpr int NC = LEAF ? 768 : 1280;
    const int p = blockIdx.x, h = threadIdx.x;
    const _Float16* G0 = G + (size_t)(2 * p) * NC;
    const _Float16* G1 = G0 + NC;
    float i0 = (float)G0[h], o0 = (float)G0[256 + h], u0 = (float)G0[512 + h];
    float i1 = (float)G1[h], o1 = (float)G1[256 + h], u1 = (float)G1[512 + h];
    float c0 = i0 * u0, c1 = i1 * u1;
    if (!LEAF) {
        float f00 = (float)G0[768 + h], f10 = (float)G0[1024 + h];
        float f01 = (float)G1[768 + h], f11 = (float)G1[1024 + h];
        c0 += f00 * csrc[(size_t)(4 * p) * 256 + h]
            + f10 * csrc[(size_t)(4 * p + 1) * 256 + h];
        c1 += f01 * csrc[(size_t)(4 * p + 2) * 256 + h]
            + f11 * csrc[(size_t)(4 * p + 3) * 256 + h];
    }
    float h0 = o0 * tanhf(c0), h1 = o1 * tanhf(c1);
    cdst[(size_t)(2 * p) * 256 + h] = c0;
    cdst[(size_t)(2 * p) * 256 + 256 + h] = c1;
    u16 hs = f2bf(h0 + h1);
    if (zrow_parent) {
        zrow_parent[(size_t)p * 512 + 256 + h] = hs;
    } else {
        size_t a = (((size_t)8 + (h >> 5)) * 64
                    + (p & 15) + (((h >> 3) & 3) << 4)) * 8 + (h & 7);
        zfrag_parent[a] = hs;
    }
}

// ---------------- small levels (n<=16): gate-parallel GEMM -> pre ----------
__global__ __launch_bounds__(64) void small_gemm(
    const u16* __restrict__ Zpk, const u16* __restrict__ Wfrag,
    const float* __restrict__ bias, float* __restrict__ pre, int n)
{
    const int lane = threadIdx.x;
    const int q = blockIdx.x;
    const int nt0 = (q >> 2) * 16 + (q & 3) * 4;
    const int cc = lane & 15, rq = (lane >> 4) * 4;

    f32x4 acc[4] = {};
    const u16* aB = Zpk + (size_t)lane * 8;
    const u16* bB = Wfrag + ((size_t)nt0 * 16 * 64 + lane) * 8;

    bf16x8 aX, bX[4], aY, bY[4];
    aX = *(const bf16x8*)(aB);
#pragma unroll
    for (int j = 0; j < 4; ++j)
        bX[j] = *(const bf16x8*)(bB + (size_t)(j * 16) * 512);

#pragma unroll
    for (int kc = 0; kc < 16; kc += 2) {
        aY = *(const bf16x8*)(aB + (size_t)(kc + 1) * 512);
#pragma unroll
        for (int j = 0; j < 4; ++j)
            bY[j] = *(const bf16x8*)(bB + (size_t)(j * 16 + kc + 1) * 512);
#pragma unroll
        for (int j = 0; j < 4; ++j)
            acc[j] = __builtin_amdgcn_mfma_f32_16x16x32_bf16(aX, bX[j], acc[j], 0, 0, 0);
        if (kc + 2 < 16) {
            aX = *(const bf16x8*)(aB + (size_t)(kc + 2) * 512);
#pragma unroll
            for (int j = 0; j < 4; ++j)
                bX[j] = *(const bf16x8*)(bB + (size_t)(j * 16 + kc + 2) * 512);
        }
#pragma unroll
        for (int j = 0; j < 4; ++j)
            acc[j] = __builtin_amdgcn_mfma_f32_16x16x32_bf16(aY, bY[j], acc[j], 0, 0, 0);
    }

#pragma unroll
    for (int j = 0; j < 4; ++j) {
        int coln = (nt0 + j) * 16 + cc;
        float bb = bias[coln];
#pragma unroll
        for (int r = 0; r < 4; ++r) {
            int row = rq + r;
            if (row < n) pre[(size_t)row * 1280 + coln] = acc[j][r] + bb;
        }
    }
}

// ---------------- small-level epilogue (pre -> c, Hs; root -> out) ----------
__global__ __launch_bounds__(256) void epi_small(
    const float* __restrict__ pre, const float* __restrict__ csrc,
    float* __restrict__ c_out, u16* __restrict__ zfrag_parent,
    float* __restrict__ root_out, int npairs)
{
    int idx = blockIdx.x * 256 + threadIdx.x;
    if (root_out) {
        int h = idx;  // 256 threads
        const float* p = pre;
        float c = sigf(p[h]) * tanhf(p[512 + h])
                + sigf(p[768 + h]) * csrc[h]
                + sigf(p[1024 + h]) * csrc[256 + h];
        root_out[h] = sigf(p[256 + h]) * tanhf(c);
        root_out[256 + h] = c;
        return;
    }
    if (idx >= npairs * 256) return;
    int pI = idx >> 8, h = idx & 255;
    int n0 = 2 * pI;
    const float* p0 = pre + (size_t)n0 * 1280;
    const float* p1 = p0 + 1280;
    float c0 = sigf(p0[h]) * tanhf(p0[512 + h])
             + sigf(p0[768 + h]) * csrc[(size_t)(2 * n0) * 256 + h]
             + sigf(p0[1024 + h]) * csrc[(size_t)(2 * n0 + 1) * 256 + h];
    float c1 = sigf(p1[h]) * tanhf(p1[512 + h])
             + sigf(p1[768 + h]) * csrc[(size_t)(2 * n0 + 2) * 256 + h]
             + sigf(p1[1024 + h]) * csrc[(size_t)(2 * n0 + 3) * 256 + h];
    float h0 = sigf(p0[256 + h]) * tanhf(c0);
    float h1 = sigf(p1[256 + h]) * tanhf(c1);
    c_out[(size_t)n0 * 256 + h] = c0;
    c_out[(size_t)(n0 + 1) * 256 + h] = c1;
    size_t a = (((size_t)8 + (h >> 5)) * 64
                + (pI & 15) + (((h >> 3) & 3) << 4)) * 8 + (h & 7);
    zfrag_parent[a] = f2bf(h0 + h1);
}

// ---------------- launch ----------------
extern "C" void kernel_launch(void* const* d_in, const int* in_sizes, int n_in,
                              void* d_out, int out_size, void* d_ws, size_t ws_size,
                              hipStream_t stream)
{
    const float* x   = (const float*)d_in[0];
    const float* Wi  = (const float*)d_in[1];
    const float* bi  = (const float*)d_in[2];
    const float* Wf  = (const float*)d_in[3];
    const float* bf  = (const float*)d_in[4];
    const float* Wo  = (const float*)d_in[5];
    const float* bo  = (const float*)d_in[6];
    const float* Wu  = (const float*)d_in[7];
    const float* bu  = (const float*)d_in[8];
    const float* Ui  = (const float*)d_in[9];
    const float* Uo  = (const float*)d_in[10];
    const float* Uu  = (const float*)d_in[11];
    const float* Wfk = (const float*)d_in[12];
    float* out = (float*)d_out;
    char* ws   = (char*)d_ws;
    (void)ws_size; (void)in_sizes; (void)n_in; (void)out_size;

    size_t off = 0;
    u16* Wrow     = (u16*)(ws + off); off += (size_t)1280 * 512 * 2;
    u16* Wfrag    = (u16*)(ws + off); off += (size_t)1280 * 512 * 2;
    u16* WleafRow = (u16*)(ws + off); off += (size_t)768 * 256 * 2;
    float* bbig   = (float*)(ws + off); off += 1280 * 4;
    float* bleaf  = (float*)(ws + off); off += 768 * 4 + 192;                // 256B align
    u16* Xbf    = (u16*)(ws + off); off += (size_t)65536 * 256 * 2;          // 32 MB
    u16* Zrow   = (u16*)(ws + off); off += (size_t)65536 * 512 * 2;          // 64 MB
    u16* Ztiles = (u16*)(ws + off); off += (size_t)5 * 8192 * 2;             // 80 KB
    float* cA = (float*)(ws + off); off += (size_t)65536 * 256 * 4;          // 64 MB
    float* cB = (float*)(ws + off); off += (size_t)32768 * 256 * 4;          // 32 MB
    float* pre_small = (float*)(ws + off); off += (size_t)16 * 1280 * 4;
    _Float16* Ghalf = (_Float16*)(ws + off); off += (size_t)65536 * 768 * 2; // 96 MB

    auto ztile = [&](int d) -> u16* { return Ztiles + (size_t)(4 - d) * 8192; };

    // 1) pack weights + convert x
    pack_weights<<<5897, 256, 0, stream>>>(Wi, bi, Wf, bf, Wo, bo, Wu, bu,
                                           Ui, Uo, Uu, Wfk, Wrow, Wfrag, WleafRow,
                                           bbig, bleaf);
    cvt_all<<<16385, 256, 0, stream>>>(x, Zrow, Ztiles, Xbf);

    // 2) leaf: gemm (i,o,u fp16) + combine -> cA, Hs into Zrow level 15
    gate_gemm<<<dim3(LEAF_N / 128, 6), 256, 0, stream>>>(
        Xbf, 256, LEAF_N, WleafRow, 256, 256, bleaf, Ghalf, 768);
    combine<true><<<LEAF_N / 2, 256, 0, stream>>>(
        Ghalf, nullptr, cA, Zrow + zrowOff(15), nullptr);

    // 3) internal levels d=15..5
    for (int d = 15; d >= 5; d--) {
        int n = 1 << d;
        float* csrc = (d & 1) ? cA : cB;
        float* cdst = (d & 1) ? cB : cA;
        gate_gemm<<<dim3((n + 127) / 128, 10), 256, 0, stream>>>(
            Zrow + zrowOff(d), 512, n, Wrow, 512, 512, bbig, Ghalf, 1280);
        if (d >= 6)
            combine<false><<<n / 2, 256, 0, stream>>>(
                Ghalf, csrc, cdst, Zrow + zrowOff(d - 1), nullptr);
        else
            combine<false><<<n / 2, 256, 0, stream>>>(
                Ghalf, csrc, cdst, nullptr, ztile(4));
    }

    // 4) small levels d=4..1: frag-major gate-parallel gemm + epilogue
    for (int d = 4; d >= 1; d--) {
        int n = 1 << d;
        float* csrc = (d & 1) ? cA : cB;
        float* cdst = (d & 1) ? cB : cA;
        small_gemm<<<20, 64, 0, stream>>>(ztile(d), Wfrag, bbig, pre_small, n);
        epi_small<<<n / 2, 256, 0, stream>>>(pre_small, csrc, cdst,
                                             ztile(d - 1), nullptr, n / 2);
    }

    // 5) root: gemm + epilogue straight to out = [h(256)|c(256)]
    small_gemm<<<20, 64, 0, stream>>>(ztile(0), Wfrag, bbig, pre_small, 1);
    epi_small<<<1, 256, 0, stream>>>(pre_small, cB, nullptr, nullptr, out, 0);
}

// Round 9
// 928.603 us; speedup vs baseline: 1.3041x; 1.0688x over previous
//
#include <hip/hip_runtime.h>
#include <math.h>

// NaryTreeLSTM on MI355X — round 9: R8 structure + two fixes.
// (1) Fast transcendentals (v_exp_f32/v_rcp_f32) — R8's libm tanhf/sigf in the
//     GEMM epilogue cost ~2.5k VALU instr/thread and made the gemm SLOWER than
//     R2's fp32-writing version (182 vs 130 us, VALUBusy 25%).
// (2) m97-style staging: unpadded LDS + global_load_lds width=16 (the
//     validated 517->874 TF step on the learn_hip ladder). BK=64.
// Everything else identical to R8 (two-stage per level, fp16 activated gates,
// lean combine, frag-major small levels).

#define LEAF_N 65536

typedef __attribute__((ext_vector_type(8))) short bf16x8;
typedef __attribute__((ext_vector_type(4))) float f32x4;
typedef unsigned short u16;

__device__ __forceinline__ float fast_sig(float x) {
    return __builtin_amdgcn_rcpf(1.0f + __expf(-x));
}
__device__ __forceinline__ float fast_tanh(float x) {
    return 2.0f * __builtin_amdgcn_rcpf(1.0f + __expf(-2.0f * x)) - 1.0f;
}

__device__ __forceinline__ u16 f2bf(float f) {
    union { float f; unsigned u; } v; v.f = f;
    unsigned r = v.u + 0x7fffu + ((v.u >> 16) & 1u);   // RNE
    return (u16)(r >> 16);
}

// row-major Z offset (elems) for levels d in [5,15]
__host__ __device__ __forceinline__ size_t zrowOff(int d) {
    return (size_t)(65536 - (2 << d)) * 512;
}

__device__ __forceinline__ void gld_lds16(const u16* g, u16* s) {
    __builtin_amdgcn_global_load_lds(
        (const __attribute__((address_space(1))) void*)g,
        (__attribute__((address_space(3))) void*)s, 16, 0, 0);
}

// ---------------- weight packing ----------------
// Wrow: row-major 1280x512 ([i|Ui],[o|Uo],[u|Uu],[f|Wfk0],[f|Wfk1])
// Wfrag: frag-major same matrix (small_gemm):
//   addr = ((nt*16+kc)*64 + l)*8 + j ; row=nt*16+(l&15), k=kc*32+(l>>4)*8+j
// WleafRow: row-major 768x256 ([i;o;u])
__global__ __launch_bounds__(256) void pack_weights(
    const float* __restrict__ Wi, const float* __restrict__ bi,
    const float* __restrict__ Wf, const float* __restrict__ bf,
    const float* __restrict__ Wo, const float* __restrict__ bo,
    const float* __restrict__ Wu, const float* __restrict__ bu,
    const float* __restrict__ Ui, const float* __restrict__ Uo,
    const float* __restrict__ Uu, const float* __restrict__ Wfk,
    u16* __restrict__ Wrow, u16* __restrict__ Wfrag, u16* __restrict__ WleafRow,
    float* __restrict__ bbig, float* __restrict__ bleaf)
{
    int idx = blockIdx.x * 256 + threadIdx.x;
    const int NWB = 1280 * 512;
    const int NWL = 768 * 256;

    auto bigval = [&](int row, int k) -> float {
        int g = row >> 8, rr = row & 255;
        if (k < 256) {
            const float* W = (g == 0) ? Wi : (g == 1) ? Wo : (g == 2) ? Wu : Wf;
            return W[rr * 256 + k];
        }
        int kk = k - 256;
        return (g == 0) ? Ui[rr * 256 + kk]
             : (g == 1) ? Uo[rr * 256 + kk]
             : (g == 2) ? Uu[rr * 256 + kk]
             : (g == 3) ? Wfk[rr * 256 + kk]
                        : Wfk[65536 + rr * 256 + kk];
    };

    if (idx < NWB) {
        Wrow[idx] = f2bf(bigval(idx >> 9, idx & 511));
    } else if (idx < 2 * NWB) {
        int q = idx - NWB;
        int j = q & 7, l = (q >> 3) & 63, kc = (q >> 9) & 15, nt = q >> 13;
        int row = nt * 16 + (l & 15);
        int k = kc * 32 + ((l >> 4) << 3) + j;
        Wfrag[q] = f2bf(bigval(row, k));
    } else if (idx < 2 * NWB + NWL) {
        int q = idx - 2 * NWB;
        int r = q >> 8, k = q & 255;
        int g = r >> 8, rr = r & 255;
        const float* W = (g == 0) ? Wi : (g == 1) ? Wo : Wu;
        WleafRow[q] = f2bf(W[rr * 256 + k]);
    } else if (idx < 2 * NWB + NWL + 1280) {
        int r = idx - 2 * NWB - NWL;
        int g = r >> 8, rr = r & 255;
        bbig[r] = (g == 0) ? bi[rr] : (g == 1) ? bo[rr] : (g == 2) ? bu[rr] : bf[rr];
    } else if (idx < 2 * NWB + NWL + 1280 + 768) {
        int r = idx - 2 * NWB - NWL - 1280;
        int g = r >> 8, rr = r & 255;
        bleaf[r] = (g == 0) ? bi[rr] : (g == 1) ? bo[rr] : bu[rr];
    }
}

// ---------------- x -> bf16 conversion ----------------
// d>=5: row-major Zrow; d<=4: frag-major tile at Ztiles+(4-d)*8192; leaf: Xbf.
__global__ __launch_bounds__(256) void cvt_all(
    const float* __restrict__ x, u16* __restrict__ Zrow,
    u16* __restrict__ Ztiles, u16* __restrict__ Xbf)
{
    int idx = blockIdx.x * 256 + threadIdx.x;
    if (idx >= 131071 * 32) return;
    int row = idx >> 5, k8 = idx & 31;
    const float* s = x + (size_t)row * 256 + k8 * 8;
    u16 r[8];
#pragma unroll
    for (int i = 0; i < 8; i++) r[i] = f2bf(s[i]);
    if (row < 65535) {
        int d = 31 - __clz(row + 1);
        int jn = row - ((1 << d) - 1);
        if (d >= 5) {
            *(uint4*)(Zrow + zrowOff(d) + (size_t)jn * 512 + k8 * 8) = *(uint4*)r;
        } else {
            int kc = k8 >> 2;
            int l = (jn & 15) + ((k8 & 3) << 4);
            size_t dst = (size_t)(4 - d) * 8192 + ((size_t)kc * 64 + l) * 8;
            *(uint4*)(Ztiles + dst) = *(uint4*)r;
        }
    } else {
        int jn = row - 65535;
        *(uint4*)(Xbf + (size_t)jn * 256 + k8 * 8) = *(uint4*)r;
    }
}

// ---------------- stage 1: gate GEMM (m97 staging) + activation epilogue ----
// C = act(A @ B^T + bias) -> fp16. act: tanh for cols [512,768), sigmoid else.
// 128x128 tile, BK=64, unpadded LDS, global_load_lds width=16.
__global__ __launch_bounds__(256) void gate_gemm(
    const u16* __restrict__ A, int lda, int M,
    const u16* __restrict__ B, int ldb, int Kdim,
    const float* __restrict__ bias, _Float16* __restrict__ G, int NC)
{
    __shared__ u16 As[128 * 64];
    __shared__ u16 Bs[128 * 64];

    const int tid  = threadIdx.x;
    const int wave = tid >> 6;
    const int lane = tid & 63;
    const int bm = blockIdx.x * 128;
    const int bn = blockIdx.y * 128;

    const int wm = (wave >> 1) * 64;
    const int wn = (wave & 1) * 64;
    const int lm = lane & 15;
    const int kq = (lane >> 4) * 8;

    // staging: inst (wave,q) covers LDS bytes [(wave*4+q)*1024, +1024),
    // i.e. rows (wave*4+q)*8 + (lane>>3), cols (lane&7)*8.
    const int srow = (lane >> 3);          // 0..7 within 8-row group
    const int scol = (lane & 7) * 8;

    f32x4 acc[4][4] = {};

    for (int k0 = 0; k0 < Kdim; k0 += 64) {
#pragma unroll
        for (int q = 0; q < 4; ++q) {
            const int grp = wave * 4 + q;              // 0..15
            const int r = grp * 8 + srow;              // 0..127
            gld_lds16(A + (size_t)(bm + r) * lda + k0 + scol,
                      As + (size_t)grp * 512 + lane * 8);
            gld_lds16(B + (size_t)(bn + r) * ldb + k0 + scol,
                      Bs + (size_t)grp * 512 + lane * 8);
        }
        __syncthreads();

#pragma unroll
        for (int kk = 0; kk < 64; kk += 32) {
            bf16x8 af[4], bfr[4];
#pragma unroll
            for (int i = 0; i < 4; i++)
                af[i] = *(const bf16x8*)(As + (wm + i * 16 + lm) * 64 + kk + kq);
#pragma unroll
            for (int j = 0; j < 4; j++)
                bfr[j] = *(const bf16x8*)(Bs + (wn + j * 16 + lm) * 64 + kk + kq);
#pragma unroll
            for (int i = 0; i < 4; i++)
#pragma unroll
                for (int j = 0; j < 4; j++)
                    acc[i][j] = __builtin_amdgcn_mfma_f32_16x16x32_bf16(
                        af[i], bfr[j], acc[i][j], 0, 0, 0);
        }
        __syncthreads();
    }

    const int cr0 = (lane >> 4) * 4;
    const int ccc = lane & 15;
#pragma unroll
    for (int i = 0; i < 4; i++) {
#pragma unroll
        for (int reg = 0; reg < 4; reg++) {
            int r = bm + wm + i * 16 + cr0 + reg;
            if (r >= M) continue;
#pragma unroll
            for (int j = 0; j < 4; j++) {
                int cn = bn + wn + j * 16 + ccc;
                float v = acc[i][j][reg] + bias[cn];
                float a = ((cn >> 8) == 2) ? fast_tanh(v) : fast_sig(v);
                G[(size_t)r * NC + cn] = (_Float16)a;
            }
        }
    }
}

// ---------------- stage 2: combine ----------------
template<bool LEAF>
__global__ __launch_bounds__(256) void combine(
    const _Float16* __restrict__ G, const float* __restrict__ csrc,
    float* __restrict__ cdst, u16* __restrict__ zrow_parent,
    u16* __restrict__ zfrag_parent)
{
    constexpr int NC = LEAF ? 768 : 1280;
    const int p = blockIdx.x, h = threadIdx.x;
    const _Float16* G0 = G + (size_t)(2 * p) * NC;
    const _Float16* G1 = G0 + NC;
    float i0 = (float)G0[h], o0 = (float)G0[256 + h], u0 = (float)G0[512 + h];
    float i1 = (float)G1[h], o1 = (float)G1[256 + h], u1 = (float)G1[512 + h];
    float c0 = i0 * u0, c1 = i1 * u1;
    if (!LEAF) {
        float f00 = (float)G0[768 + h], f10 = (float)G0[1024 + h];
        float f01 = (float)G1[768 + h], f11 = (float)G1[1024 + h];
        c0 += f00 * csrc[(size_t)(4 * p) * 256 + h]
            + f10 * csrc[(size_t)(4 * p + 1) * 256 + h];
        c1 += f01 * csrc[(size_t)(4 * p + 2) * 256 + h]
            + f11 * csrc[(size_t)(4 * p + 3) * 256 + h];
    }
    float h0 = o0 * fast_tanh(c0), h1 = o1 * fast_tanh(c1);
    cdst[(size_t)(2 * p) * 256 + h] = c0;
    cdst[(size_t)(2 * p) * 256 + 256 + h] = c1;
    u16 hs = f2bf(h0 + h1);
    if (zrow_parent) {
        zrow_parent[(size_t)p * 512 + 256 + h] = hs;
    } else {
        size_t a = (((size_t)8 + (h >> 5)) * 64
                    + (p & 15) + (((h >> 3) & 3) << 4)) * 8 + (h & 7);
        zfrag_parent[a] = hs;
    }
}

// ---------------- small levels (n<=16): gate-parallel GEMM -> pre ----------
__global__ __launch_bounds__(64) void small_gemm(
    const u16* __restrict__ Zpk, const u16* __restrict__ Wfrag,
    const float* __restrict__ bias, float* __restrict__ pre, int n)
{
    const int lane = threadIdx.x;
    const int q = blockIdx.x;
    const int nt0 = (q >> 2) * 16 + (q & 3) * 4;
    const int cc = lane & 15, rq = (lane >> 4) * 4;

    f32x4 acc[4] = {};
    const u16* aB = Zpk + (size_t)lane * 8;
    const u16* bB = Wfrag + ((size_t)nt0 * 16 * 64 + lane) * 8;

    bf16x8 aX, bX[4], aY, bY[4];
    aX = *(const bf16x8*)(aB);
#pragma unroll
    for (int j = 0; j < 4; ++j)
        bX[j] = *(const bf16x8*)(bB + (size_t)(j * 16) * 512);

#pragma unroll
    for (int kc = 0; kc < 16; kc += 2) {
        aY = *(const bf16x8*)(aB + (size_t)(kc + 1) * 512);
#pragma unroll
        for (int j = 0; j < 4; ++j)
            bY[j] = *(const bf16x8*)(bB + (size_t)(j * 16 + kc + 1) * 512);
#pragma unroll
        for (int j = 0; j < 4; ++j)
            acc[j] = __builtin_amdgcn_mfma_f32_16x16x32_bf16(aX, bX[j], acc[j], 0, 0, 0);
        if (kc + 2 < 16) {
            aX = *(const bf16x8*)(aB + (size_t)(kc + 2) * 512);
#pragma unroll
            for (int j = 0; j < 4; ++j)
                bX[j] = *(const bf16x8*)(bB + (size_t)(j * 16 + kc + 2) * 512);
        }
#pragma unroll
        for (int j = 0; j < 4; ++j)
            acc[j] = __builtin_amdgcn_mfma_f32_16x16x32_bf16(aY, bY[j], acc[j], 0, 0, 0);
    }

#pragma unroll
    for (int j = 0; j < 4; ++j) {
        int coln = (nt0 + j) * 16 + cc;
        float bb = bias[coln];
#pragma unroll
        for (int r = 0; r < 4; ++r) {
            int row = rq + r;
            if (row < n) pre[(size_t)row * 1280 + coln] = acc[j][r] + bb;
        }
    }
}

// ---------------- small-level epilogue (pre -> c, Hs; root -> out) ----------
__global__ __launch_bounds__(256) void epi_small(
    const float* __restrict__ pre, const float* __restrict__ csrc,
    float* __restrict__ c_out, u16* __restrict__ zfrag_parent,
    float* __restrict__ root_out, int npairs)
{
    int idx = blockIdx.x * 256 + threadIdx.x;
    if (root_out) {
        int h = idx;  // 256 threads
        const float* p = pre;
        float c = fast_sig(p[h]) * fast_tanh(p[512 + h])
                + fast_sig(p[768 + h]) * csrc[h]
                + fast_sig(p[1024 + h]) * csrc[256 + h];
        root_out[h] = fast_sig(p[256 + h]) * fast_tanh(c);
        root_out[256 + h] = c;
        return;
    }
    if (idx >= npairs * 256) return;
    int pI = idx >> 8, h = idx & 255;
    int n0 = 2 * pI;
    const float* p0 = pre + (size_t)n0 * 1280;
    const float* p1 = p0 + 1280;
    float c0 = fast_sig(p0[h]) * fast_tanh(p0[512 + h])
             + fast_sig(p0[768 + h]) * csrc[(size_t)(2 * n0) * 256 + h]
             + fast_sig(p0[1024 + h]) * csrc[(size_t)(2 * n0 + 1) * 256 + h];
    float c1 = fast_sig(p1[h]) * fast_tanh(p1[512 + h])
             + fast_sig(p1[768 + h]) * csrc[(size_t)(2 * n0 + 2) * 256 + h]
             + fast_sig(p1[1024 + h]) * csrc[(size_t)(2 * n0 + 3) * 256 + h];
    float h0 = fast_sig(p0[256 + h]) * fast_tanh(c0);
    float h1 = fast_sig(p1[256 + h]) * fast_tanh(c1);
    c_out[(size_t)n0 * 256 + h] = c0;
    c_out[(size_t)(n0 + 1) * 256 + h] = c1;
    size_t a = (((size_t)8 + (h >> 5)) * 64
                + (pI & 15) + (((h >> 3) & 3) << 4)) * 8 + (h & 7);
    zfrag_parent[a] = f2bf(h0 + h1);
}

// ---------------- launch ----------------
extern "C" void kernel_launch(void* const* d_in, const int* in_sizes, int n_in,
                              void* d_out, int out_size, void* d_ws, size_t ws_size,
                              hipStream_t stream)
{
    const float* x   = (const float*)d_in[0];
    const float* Wi  = (const float*)d_in[1];
    const float* bi  = (const float*)d_in[2];
    const float* Wf  = (const float*)d_in[3];
    const float* bf  = (const float*)d_in[4];
    const float* Wo  = (const float*)d_in[5];
    const float* bo  = (const float*)d_in[6];
    const float* Wu  = (const float*)d_in[7];
    const float* bu  = (const float*)d_in[8];
    const float* Ui  = (const float*)d_in[9];
    const float* Uo  = (const float*)d_in[10];
    const float* Uu  = (const float*)d_in[11];
    const float* Wfk = (const float*)d_in[12];
    float* out = (float*)d_out;
    char* ws   = (char*)d_ws;
    (void)ws_size; (void)in_sizes; (void)n_in; (void)out_size;

    size_t off = 0;
    u16* Wrow     = (u16*)(ws + off); off += (size_t)1280 * 512 * 2;
    u16* Wfrag    = (u16*)(ws + off); off += (size_t)1280 * 512 * 2;
    u16* WleafRow = (u16*)(ws + off); off += (size_t)768 * 256 * 2;
    float* bbig   = (float*)(ws + off); off += 1280 * 4;
    float* bleaf  = (float*)(ws + off); off += 768 * 4 + 192;                // 256B align
    u16* Xbf    = (u16*)(ws + off); off += (size_t)65536 * 256 * 2;          // 32 MB
    u16* Zrow   = (u16*)(ws + off); off += (size_t)65536 * 512 * 2;          // 64 MB
    u16* Ztiles = (u16*)(ws + off); off += (size_t)5 * 8192 * 2;             // 80 KB
    float* cA = (float*)(ws + off); off += (size_t)65536 * 256 * 4;          // 64 MB
    float* cB = (float*)(ws + off); off += (size_t)32768 * 256 * 4;          // 32 MB
    float* pre_small = (float*)(ws + off); off += (size_t)16 * 1280 * 4;
    _Float16* Ghalf = (_Float16*)(ws + off); off += (size_t)65536 * 768 * 2; // 96 MB

    auto ztile = [&](int d) -> u16* { return Ztiles + (size_t)(4 - d) * 8192; };

    // 1) pack weights + convert x
    pack_weights<<<5897, 256, 0, stream>>>(Wi, bi, Wf, bf, Wo, bo, Wu, bu,
                                           Ui, Uo, Uu, Wfk, Wrow, Wfrag, WleafRow,
                                           bbig, bleaf);
    cvt_all<<<16385, 256, 0, stream>>>(x, Zrow, Ztiles, Xbf);

    // 2) leaf: gemm (i,o,u fp16) + combine -> cA, Hs into Zrow level 15
    gate_gemm<<<dim3(LEAF_N / 128, 6), 256, 0, stream>>>(
        Xbf, 256, LEAF_N, WleafRow, 256, 256, bleaf, Ghalf, 768);
    combine<true><<<LEAF_N / 2, 256, 0, stream>>>(
        Ghalf, nullptr, cA, Zrow + zrowOff(15), nullptr);

    // 3) internal levels d=15..5
    for (int d = 15; d >= 5; d--) {
        int n = 1 << d;
        float* csrc = (d & 1) ? cA : cB;
        float* cdst = (d & 1) ? cB : cA;
        gate_gemm<<<dim3((n + 127) / 128, 10), 256, 0, stream>>>(
            Zrow + zrowOff(d), 512, n, Wrow, 512, 512, bbig, Ghalf, 1280);
        if (d >= 6)
            combine<false><<<n / 2, 256, 0, stream>>>(
                Ghalf, csrc, cdst, Zrow + zrowOff(d - 1), nullptr);
        else
            combine<false><<<n / 2, 256, 0, stream>>>(
                Ghalf, csrc, cdst, nullptr, ztile(4));
    }

    // 4) small levels d=4..1: frag-major gate-parallel gemm + epilogue
    for (int d = 4; d >= 1; d--) {
        int n = 1 << d;
        float* csrc = (d & 1) ? cA : cB;
        float* cdst = (d & 1) ? cB : cA;
        small_gemm<<<20, 64, 0, stream>>>(ztile(d), Wfrag, bbig, pre_small, n);
        epi_small<<<n / 2, 256, 0, stream>>>(pre_small, csrc, cdst,
                                             ztile(d - 1), nullptr, n / 2);
    }

    // 5) root: gemm + epilogue straight to out = [h(256)|c(256)]
    small_gemm<<<20, 64, 0, stream>>>(ztile(0), Wfrag, bbig, pre_small, 1);
    epi_small<<<1, 256, 0, stream>>>(pre_small, cB, nullptr, nullptr, out, 0);
}

// Round 10
// 825.337 us; speedup vs baseline: 1.4673x; 1.1251x over previous
//
#include <hip/hip_runtime.h>
#include <math.h>

// NaryTreeLSTM on MI355X — round 10: R9 + XOR-swizzled LDS staging.
// R9 diagnosis: unpadded LDS rows (64 elems = 128 B = 32 banks) made every
// fragment ds_read_b128 a 16-way bank conflict (SQ_LDS_BANK_CONFLICT=1.57e7,
// ~5.7x LDS cost, K-loop LDS-bound at MfmaUtil 12%). Fix: lane l stages
// global col ((l&7)^(l>>3))*8 of its row (same 128B segment -> DMA coalescing
// unchanged); LDS addr = row*64 + ((c^(row&7))*8). Fragment reads use
// sw = (chunk ^ (row&7)) -> uniform 2-way bank aliasing (free, m136).
// Everything else identical to R9.

#define LEAF_N 65536

typedef __attribute__((ext_vector_type(8))) short bf16x8;
typedef __attribute__((ext_vector_type(4))) float f32x4;
typedef unsigned short u16;

__device__ __forceinline__ float fast_sig(float x) {
    return __builtin_amdgcn_rcpf(1.0f + __expf(-x));
}
__device__ __forceinline__ float fast_tanh(float x) {
    return 2.0f * __builtin_amdgcn_rcpf(1.0f + __expf(-2.0f * x)) - 1.0f;
}

__device__ __forceinline__ u16 f2bf(float f) {
    union { float f; unsigned u; } v; v.f = f;
    unsigned r = v.u + 0x7fffu + ((v.u >> 16) & 1u);   // RNE
    return (u16)(r >> 16);
}

// row-major Z offset (elems) for levels d in [5,15]
__host__ __device__ __forceinline__ size_t zrowOff(int d) {
    return (size_t)(65536 - (2 << d)) * 512;
}

__device__ __forceinline__ void gld_lds16(const u16* g, u16* s) {
    __builtin_amdgcn_global_load_lds(
        (const __attribute__((address_space(1))) void*)g,
        (__attribute__((address_space(3))) void*)s, 16, 0, 0);
}

// ---------------- weight packing ----------------
// Wrow: row-major 1280x512 ([i|Ui],[o|Uo],[u|Uu],[f|Wfk0],[f|Wfk1])
// Wfrag: frag-major same matrix (small_gemm):
//   addr = ((nt*16+kc)*64 + l)*8 + j ; row=nt*16+(l&15), k=kc*32+(l>>4)*8+j
// WleafRow: row-major 768x256 ([i;o;u])
__global__ __launch_bounds__(256) void pack_weights(
    const float* __restrict__ Wi, const float* __restrict__ bi,
    const float* __restrict__ Wf, const float* __restrict__ bf,
    const float* __restrict__ Wo, const float* __restrict__ bo,
    const float* __restrict__ Wu, const float* __restrict__ bu,
    const float* __restrict__ Ui, const float* __restrict__ Uo,
    const float* __restrict__ Uu, const float* __restrict__ Wfk,
    u16* __restrict__ Wrow, u16* __restrict__ Wfrag, u16* __restrict__ WleafRow,
    float* __restrict__ bbig, float* __restrict__ bleaf)
{
    int idx = blockIdx.x * 256 + threadIdx.x;
    const int NWB = 1280 * 512;
    const int NWL = 768 * 256;

    auto bigval = [&](int row, int k) -> float {
        int g = row >> 8, rr = row & 255;
        if (k < 256) {
            const float* W = (g == 0) ? Wi : (g == 1) ? Wo : (g == 2) ? Wu : Wf;
            return W[rr * 256 + k];
        }
        int kk = k - 256;
        return (g == 0) ? Ui[rr * 256 + kk]
             : (g == 1) ? Uo[rr * 256 + kk]
             : (g == 2) ? Uu[rr * 256 + kk]
             : (g == 3) ? Wfk[rr * 256 + kk]
                        : Wfk[65536 + rr * 256 + kk];
    };

    if (idx < NWB) {
        Wrow[idx] = f2bf(bigval(idx >> 9, idx & 511));
    } else if (idx < 2 * NWB) {
        int q = idx - NWB;
        int j = q & 7, l = (q >> 3) & 63, kc = (q >> 9) & 15, nt = q >> 13;
        int row = nt * 16 + (l & 15);
        int k = kc * 32 + ((l >> 4) << 3) + j;
        Wfrag[q] = f2bf(bigval(row, k));
    } else if (idx < 2 * NWB + NWL) {
        int q = idx - 2 * NWB;
        int r = q >> 8, k = q & 255;
        int g = r >> 8, rr = r & 255;
        const float* W = (g == 0) ? Wi : (g == 1) ? Wo : Wu;
        WleafRow[q] = f2bf(W[rr * 256 + k]);
    } else if (idx < 2 * NWB + NWL + 1280) {
        int r = idx - 2 * NWB - NWL;
        int g = r >> 8, rr = r & 255;
        bbig[r] = (g == 0) ? bi[rr] : (g == 1) ? bo[rr] : (g == 2) ? bu[rr] : bf[rr];
    } else if (idx < 2 * NWB + NWL + 1280 + 768) {
        int r = idx - 2 * NWB - NWL - 1280;
        int g = r >> 8, rr = r & 255;
        bleaf[r] = (g == 0) ? bi[rr] : (g == 1) ? bo[rr] : bu[rr];
    }
}

// ---------------- x -> bf16 conversion ----------------
// d>=5: row-major Zrow; d<=4: frag-major tile at Ztiles+(4-d)*8192; leaf: Xbf.
__global__ __launch_bounds__(256) void cvt_all(
    const float* __restrict__ x, u16* __restrict__ Zrow,
    u16* __restrict__ Ztiles, u16* __restrict__ Xbf)
{
    int idx = blockIdx.x * 256 + threadIdx.x;
    if (idx >= 131071 * 32) return;
    int row = idx >> 5, k8 = idx & 31;
    const float* s = x + (size_t)row * 256 + k8 * 8;
    u16 r[8];
#pragma unroll
    for (int i = 0; i < 8; i++) r[i] = f2bf(s[i]);
    if (row < 65535) {
        int d = 31 - __clz(row + 1);
        int jn = row - ((1 << d) - 1);
        if (d >= 5) {
            *(uint4*)(Zrow + zrowOff(d) + (size_t)jn * 512 + k8 * 8) = *(uint4*)r;
        } else {
            int kc = k8 >> 2;
            int l = (jn & 15) + ((k8 & 3) << 4);
            size_t dst = (size_t)(4 - d) * 8192 + ((size_t)kc * 64 + l) * 8;
            *(uint4*)(Ztiles + dst) = *(uint4*)r;
        }
    } else {
        int jn = row - 65535;
        *(uint4*)(Xbf + (size_t)jn * 256 + k8 * 8) = *(uint4*)r;
    }
}

// ---------------- stage 1: gate GEMM (swizzled m97 staging) ----------------
// C = act(A @ B^T + bias) -> fp16. act: tanh for cols [512,768), sigmoid else.
// 128x128 tile, BK=64, global_load_lds width=16, XOR-swizzled LDS layout:
//   LDS elem addr = row*64 + ((chunk ^ (row&7)) * 8),  chunk = col/8.
__global__ __launch_bounds__(256) void gate_gemm(
    const u16* __restrict__ A, int lda, int M,
    const u16* __restrict__ B, int ldb, int Kdim,
    const float* __restrict__ bias, _Float16* __restrict__ G, int NC)
{
    __shared__ u16 As[128 * 64];
    __shared__ u16 Bs[128 * 64];

    const int tid  = threadIdx.x;
    const int wave = tid >> 6;
    const int lane = tid & 63;
    const int bm = blockIdx.x * 128;
    const int bn = blockIdx.y * 128;

    const int wm = (wave >> 1) * 64;
    const int wn = (wave & 1) * 64;
    const int lm = lane & 15;
    const int q4 = lane >> 4;              // k-quarter 0..3

    // staging: inst (wave,q) covers LDS bytes [(wave*4+q)*1024, +1024) =
    // rows grp*8+(lane>>3); lane fetches swizzled col ((lane&7)^(lane>>3))*8.
    const int srow = lane >> 3;            // 0..7 within 8-row group
    const int scol = ((lane & 7) ^ srow) * 8;

    f32x4 acc[4][4] = {};

    for (int k0 = 0; k0 < Kdim; k0 += 64) {
#pragma unroll
        for (int q = 0; q < 4; ++q) {
            const int grp = wave * 4 + q;              // 0..15
            const int r = grp * 8 + srow;              // 0..127
            gld_lds16(A + (size_t)(bm + r) * lda + k0 + scol,
                      As + (size_t)grp * 512 + lane * 8);
            gld_lds16(B + (size_t)(bn + r) * ldb + k0 + scol,
                      Bs + (size_t)grp * 512 + lane * 8);
        }
        __syncthreads();

#pragma unroll
        for (int kk = 0; kk < 64; kk += 32) {
            const int sw = (((kk >> 3) + q4) ^ (lm & 7)) << 3;  // swizzled col
            bf16x8 af[4], bfr[4];
#pragma unroll
            for (int i = 0; i < 4; i++)
                af[i] = *(const bf16x8*)(As + (wm + i * 16 + lm) * 64 + sw);
#pragma unroll
            for (int j = 0; j < 4; j++)
                bfr[j] = *(const bf16x8*)(Bs + (wn + j * 16 + lm) * 64 + sw);
#pragma unroll
            for (int i = 0; i < 4; i++)
#pragma unroll
                for (int j = 0; j < 4; j++)
                    acc[i][j] = __builtin_amdgcn_mfma_f32_16x16x32_bf16(
                        af[i], bfr[j], acc[i][j], 0, 0, 0);
        }
        __syncthreads();
    }

    const int cr0 = q4 * 4;
    const int ccc = lm;
#pragma unroll
    for (int i = 0; i < 4; i++) {
#pragma unroll
        for (int reg = 0; reg < 4; reg++) {
            int r = bm + wm + i * 16 + cr0 + reg;
            if (r >= M) continue;
#pragma unroll
            for (int j = 0; j < 4; j++) {
                int cn = bn + wn + j * 16 + ccc;
                float v = acc[i][j][reg] + bias[cn];
                float a = ((cn >> 8) == 2) ? fast_tanh(v) : fast_sig(v);
                G[(size_t)r * NC + cn] = (_Float16)a;
            }
        }
    }
}

// ---------------- stage 2: combine ----------------
template<bool LEAF>
__global__ __launch_bounds__(256) void combine(
    const _Float16* __restrict__ G, const float* __restrict__ csrc,
    float* __restrict__ cdst, u16* __restrict__ zrow_parent,
    u16* __restrict__ zfrag_parent)
{
    constexpr int NC = LEAF ? 768 : 1280;
    const int p = blockIdx.x, h = threadIdx.x;
    const _Float16* G0 = G + (size_t)(2 * p) * NC;
    const _Float16* G1 = G0 + NC;
    float i0 = (float)G0[h], o0 = (float)G0[256 + h], u0 = (float)G0[512 + h];
    float i1 = (float)G1[h], o1 = (float)G1[256 + h], u1 = (float)G1[512 + h];
    float c0 = i0 * u0, c1 = i1 * u1;
    if (!LEAF) {
        float f00 = (float)G0[768 + h], f10 = (float)G0[1024 + h];
        float f01 = (float)G1[768 + h], f11 = (float)G1[1024 + h];
        c0 += f00 * csrc[(size_t)(4 * p) * 256 + h]
            + f10 * csrc[(size_t)(4 * p + 1) * 256 + h];
        c1 += f01 * csrc[(size_t)(4 * p + 2) * 256 + h]
            + f11 * csrc[(size_t)(4 * p + 3) * 256 + h];
    }
    float h0 = o0 * fast_tanh(c0), h1 = o1 * fast_tanh(c1);
    cdst[(size_t)(2 * p) * 256 + h] = c0;
    cdst[(size_t)(2 * p) * 256 + 256 + h] = c1;
    u16 hs = f2bf(h0 + h1);
    if (zrow_parent) {
        zrow_parent[(size_t)p * 512 + 256 + h] = hs;
    } else {
        size_t a = (((size_t)8 + (h >> 5)) * 64
                    + (p & 15) + (((h >> 3) & 3) << 4)) * 8 + (h & 7);
        zfrag_parent[a] = hs;
    }
}

// ---------------- small levels (n<=16): gate-parallel GEMM -> pre ----------
__global__ __launch_bounds__(64) void small_gemm(
    const u16* __restrict__ Zpk, const u16* __restrict__ Wfrag,
    const float* __restrict__ bias, float* __restrict__ pre, int n)
{
    const int lane = threadIdx.x;
    const int q = blockIdx.x;
    const int nt0 = (q >> 2) * 16 + (q & 3) * 4;
    const int cc = lane & 15, rq = (lane >> 4) * 4;

    f32x4 acc[4] = {};
    const u16* aB = Zpk + (size_t)lane * 8;
    const u16* bB = Wfrag + ((size_t)nt0 * 16 * 64 + lane) * 8;

    bf16x8 aX, bX[4], aY, bY[4];
    aX = *(const bf16x8*)(aB);
#pragma unroll
    for (int j = 0; j < 4; ++j)
        bX[j] = *(const bf16x8*)(bB + (size_t)(j * 16) * 512);

#pragma unroll
    for (int kc = 0; kc < 16; kc += 2) {
        aY = *(const bf16x8*)(aB + (size_t)(kc + 1) * 512);
#pragma unroll
        for (int j = 0; j < 4; ++j)
            bY[j] = *(const bf16x8*)(bB + (size_t)(j * 16 + kc + 1) * 512);
#pragma unroll
        for (int j = 0; j < 4; ++j)
            acc[j] = __builtin_amdgcn_mfma_f32_16x16x32_bf16(aX, bX[j], acc[j], 0, 0, 0);
        if (kc + 2 < 16) {
            aX = *(const bf16x8*)(aB + (size_t)(kc + 2) * 512);
#pragma unroll
            for (int j = 0; j < 4; ++j)
                bX[j] = *(const bf16x8*)(bB + (size_t)(j * 16 + kc + 2) * 512);
        }
#pragma unroll
        for (int j = 0; j < 4; ++j)
            acc[j] = __builtin_amdgcn_mfma_f32_16x16x32_bf16(aY, bY[j], acc[j], 0, 0, 0);
    }

#pragma unroll
    for (int j = 0; j < 4; ++j) {
        int coln = (nt0 + j) * 16 + cc;
        float bb = bias[coln];
#pragma unroll
        for (int r = 0; r < 4; ++r) {
            int row = rq + r;
            if (row < n) pre[(size_t)row * 1280 + coln] = acc[j][r] + bb;
        }
    }
}

// ---------------- small-level epilogue (pre -> c, Hs; root -> out) ----------
__global__ __launch_bounds__(256) void epi_small(
    const float* __restrict__ pre, const float* __restrict__ csrc,
    float* __restrict__ c_out, u16* __restrict__ zfrag_parent,
    float* __restrict__ root_out, int npairs)
{
    int idx = blockIdx.x * 256 + threadIdx.x;
    if (root_out) {
        int h = idx;  // 256 threads
        const float* p = pre;
        float c = fast_sig(p[h]) * fast_tanh(p[512 + h])
                + fast_sig(p[768 + h]) * csrc[h]
                + fast_sig(p[1024 + h]) * csrc[256 + h];
        root_out[h] = fast_sig(p[256 + h]) * fast_tanh(c);
        root_out[256 + h] = c;
        return;
    }
    if (idx >= npairs * 256) return;
    int pI = idx >> 8, h = idx & 255;
    int n0 = 2 * pI;
    const float* p0 = pre + (size_t)n0 * 1280;
    const float* p1 = p0 + 1280;
    float c0 = fast_sig(p0[h]) * fast_tanh(p0[512 + h])
             + fast_sig(p0[768 + h]) * csrc[(size_t)(2 * n0) * 256 + h]
             + fast_sig(p0[1024 + h]) * csrc[(size_t)(2 * n0 + 1) * 256 + h];
    float c1 = fast_sig(p1[h]) * fast_tanh(p1[512 + h])
             + fast_sig(p1[768 + h]) * csrc[(size_t)(2 * n0 + 2) * 256 + h]
             + fast_sig(p1[1024 + h]) * csrc[(size_t)(2 * n0 + 3) * 256 + h];
    float h0 = fast_sig(p0[256 + h]) * fast_tanh(c0);
    float h1 = fast_sig(p1[256 + h]) * fast_tanh(c1);
    c_out[(size_t)n0 * 256 + h] = c0;
    c_out[(size_t)(n0 + 1) * 256 + h] = c1;
    size_t a = (((size_t)8 + (h >> 5)) * 64
                + (pI & 15) + (((h >> 3) & 3) << 4)) * 8 + (h & 7);
    zfrag_parent[a] = f2bf(h0 + h1);
}

// ---------------- launch ----------------
extern "C" void kernel_launch(void* const* d_in, const int* in_sizes, int n_in,
                              void* d_out, int out_size, void* d_ws, size_t ws_size,
                              hipStream_t stream)
{
    const float* x   = (const float*)d_in[0];
    const float* Wi  = (const float*)d_in[1];
    const float* bi  = (const float*)d_in[2];
    const float* Wf  = (const float*)d_in[3];
    const float* bf  = (const float*)d_in[4];
    const float* Wo  = (const float*)d_in[5];
    const float* bo  = (const float*)d_in[6];
    const float* Wu  = (const float*)d_in[7];
    const float* bu  = (const float*)d_in[8];
    const float* Ui  = (const float*)d_in[9];
    const float* Uo  = (const float*)d_in[10];
    const float* Uu  = (const float*)d_in[11];
    const float* Wfk = (const float*)d_in[12];
    float* out = (float*)d_out;
    char* ws   = (char*)d_ws;
    (void)ws_size; (void)in_sizes; (void)n_in; (void)out_size;

    size_t off = 0;
    u16* Wrow     = (u16*)(ws + off); off += (size_t)1280 * 512 * 2;
    u16* Wfrag    = (u16*)(ws + off); off += (size_t)1280 * 512 * 2;
    u16* WleafRow = (u16*)(ws + off); off += (size_t)768 * 256 * 2;
    float* bbig   = (float*)(ws + off); off += 1280 * 4;
    float* bleaf  = (float*)(ws + off); off += 768 * 4 + 192;                // 256B align
    u16* Xbf    = (u16*)(ws + off); off += (size_t)65536 * 256 * 2;          // 32 MB
    u16* Zrow   = (u16*)(ws + off); off += (size_t)65536 * 512 * 2;          // 64 MB
    u16* Ztiles = (u16*)(ws + off); off += (size_t)5 * 8192 * 2;             // 80 KB
    float* cA = (float*)(ws + off); off += (size_t)65536 * 256 * 4;          // 64 MB
    float* cB = (float*)(ws + off); off += (size_t)32768 * 256 * 4;          // 32 MB
    float* pre_small = (float*)(ws + off); off += (size_t)16 * 1280 * 4;
    _Float16* Ghalf = (_Float16*)(ws + off); off += (size_t)65536 * 768 * 2; // 96 MB

    auto ztile = [&](int d) -> u16* { return Ztiles + (size_t)(4 - d) * 8192; };

    // 1) pack weights + convert x
    pack_weights<<<5897, 256, 0, stream>>>(Wi, bi, Wf, bf, Wo, bo, Wu, bu,
                                           Ui, Uo, Uu, Wfk, Wrow, Wfrag, WleafRow,
                                           bbig, bleaf);
    cvt_all<<<16385, 256, 0, stream>>>(x, Zrow, Ztiles, Xbf);

    // 2) leaf: gemm (i,o,u fp16) + combine -> cA, Hs into Zrow level 15
    gate_gemm<<<dim3(LEAF_N / 128, 6), 256, 0, stream>>>(
        Xbf, 256, LEAF_N, WleafRow, 256, 256, bleaf, Ghalf, 768);
    combine<true><<<LEAF_N / 2, 256, 0, stream>>>(
        Ghalf, nullptr, cA, Zrow + zrowOff(15), nullptr);

    // 3) internal levels d=15..5
    for (int d = 15; d >= 5; d--) {
        int n = 1 << d;
        float* csrc = (d & 1) ? cA : cB;
        float* cdst = (d & 1) ? cB : cA;
        gate_gemm<<<dim3((n + 127) / 128, 10), 256, 0, stream>>>(
            Zrow + zrowOff(d), 512, n, Wrow, 512, 512, bbig, Ghalf, 1280);
        if (d >= 6)
            combine<false><<<n / 2, 256, 0, stream>>>(
                Ghalf, csrc, cdst, Zrow + zrowOff(d - 1), nullptr);
        else
            combine<false><<<n / 2, 256, 0, stream>>>(
                Ghalf, csrc, cdst, nullptr, ztile(4));
    }

    // 4) small levels d=4..1: frag-major gate-parallel gemm + epilogue
    for (int d = 4; d >= 1; d--) {
        int n = 1 << d;
        float* csrc = (d & 1) ? cA : cB;
        float* cdst = (d & 1) ? cB : cA;
        small_gemm<<<20, 64, 0, stream>>>(ztile(d), Wfrag, bbig, pre_small, n);
        epi_small<<<n / 2, 256, 0, stream>>>(pre_small, csrc, cdst,
                                             ztile(d - 1), nullptr, n / 2);
    }

    // 5) root: gemm + epilogue straight to out = [h(256)|c(256)]
    small_gemm<<<20, 64, 0, stream>>>(ztile(0), Wfrag, bbig, pre_small, 1);
    epi_small<<<1, 256, 0, stream>>>(pre_small, cB, nullptr, nullptr, out, 0);
}